// Round 4
// baseline (152.881 us; speedup 1.0000x reference)
//
#include <hip/hip_runtime.h>
#include <math.h>

// Problem constants
#define B_ 4
#define S_ 1024
#define HID_ 1024
#define NH_ 16
#define HD_ 64
#define NTOK (B_ * S_)           // 4096

typedef __attribute__((ext_vector_type(4))) float f32x4;
typedef __attribute__((ext_vector_type(16))) float f32x16;
typedef __attribute__((ext_vector_type(8))) short bf16x8;   // 8 bf16 = 4 VGPRs

__device__ __forceinline__ unsigned short f2bf(float f) {
    union { float f; unsigned int u; } v; v.f = f;
    unsigned int r = v.u + 0x7fffu + ((v.u >> 16) & 1u);   // RNE
    return (unsigned short)(r >> 16);
}

// Packed f32->bf16 (RNE). gfx950 has v_cvt_pk_bf16_f32; fall back to software.
#if __has_builtin(__builtin_amdgcn_cvt_pk_bf16_f32)
__device__ __forceinline__ unsigned int pk_bf16(float a, float b) {
    auto v = __builtin_amdgcn_cvt_pk_bf16_f32(a, b);   // elem0=a (low), elem1=b (high)
    union { decltype(v) v; unsigned int u; } cv; cv.v = v;
    return cv.u;
}
#else
__device__ __forceinline__ unsigned int pk_bf16(float a, float b) {
    return (unsigned int)f2bf(a) | ((unsigned int)f2bf(b) << 16);
}
#endif

// permlane32_swap: (a,b) -> a' = {a.lo, b.lo}, b' = {a.hi, b.hi}
#if __has_builtin(__builtin_amdgcn_permlane32_swap)
__device__ __forceinline__ void plswap(unsigned &a, unsigned &b) {
    typedef __attribute__((ext_vector_type(2))) int v2i;
    v2i r = __builtin_amdgcn_permlane32_swap((int)a, (int)b, false, false);
    a = (unsigned)r[0]; b = (unsigned)r[1];
}
#else
__device__ __forceinline__ void plswap(unsigned &a, unsigned &b) {
    const unsigned bl = __shfl_xor(b, 32);
    const unsigned ah = __shfl_xor(a, 32);
    const bool hi = ((threadIdx.x & 63) >> 5) != 0;
    const unsigned na = hi ? bl : a;
    const unsigned nb = hi ? b  : ah;
    a = na; b = nb;
}
#endif

// async global->LDS, 16 B per lane. LDS dest = wave-uniform base + lane*16.
__device__ __forceinline__ void load_lds16(const void* g, void* l) {
    __builtin_amdgcn_global_load_lds(
        (const __attribute__((address_space(1))) unsigned int*)(uintptr_t)g,
        (__attribute__((address_space(3))) unsigned int*)(uintptr_t)l,
        16, 0, 0);
}

// ---------------------------------------------------------------------------
// Kernel 0: f32 -> bf16 convert for x, Wq, Wk, Wv  (packed cvt)
// ---------------------------------------------------------------------------
__global__ __launch_bounds__(256) void cvt_all(
    const float* __restrict__ x, const float* __restrict__ wq,
    const float* __restrict__ wk, const float* __restrict__ wv,
    unsigned short* __restrict__ xb, unsigned short* __restrict__ wqb,
    unsigned short* __restrict__ wkb, unsigned short* __restrict__ wvb)
{
    const int which = blockIdx.y;
    const float* src = which == 0 ? x : which == 1 ? wq : which == 2 ? wk : wv;
    unsigned short* dst = which == 0 ? xb : which == 1 ? wqb : which == 2 ? wkb : wvb;
    const int n4 = (which == 0) ? (NTOK * HID_ / 4) : (HID_ * HID_ / 4);
    int i = blockIdx.x * 256 + threadIdx.x;
    if (i < n4) {
        float4 f = ((const float4*)src)[i];
        uint2 o;
        o.x = pk_bf16(f.x, f.y);
        o.y = pk_bf16(f.z, f.w);
        ((uint2*)dst)[i] = o;
    }
}

// ---------------------------------------------------------------------------
// Kernel 1: QKV projection, bf16 MFMA. 128x128 tile, BK=64, XOR-swizzled LDS,
// 512 threads / 8 waves (wave owns 64x32). Unchanged.
// ---------------------------------------------------------------------------
__global__ __launch_bounds__(512, 6) void qkv_gemm_mfma(
    const unsigned short* __restrict__ xb,
    const unsigned short* __restrict__ Wqb, const float* __restrict__ bq,
    const unsigned short* __restrict__ Wkb, const float* __restrict__ bk,
    const unsigned short* __restrict__ Wvb, const float* __restrict__ bv,
    unsigned short* __restrict__ qout, unsigned short* __restrict__ kout,
    unsigned short* __restrict__ vtout)
{
    const int which = blockIdx.z;
    const unsigned short* __restrict__ W = which == 0 ? Wqb : which == 1 ? Wkb : Wvb;
    const float* __restrict__ bias       = which == 0 ? bq  : which == 1 ? bk  : bv;

    __shared__ unsigned short As[128 * 64];   // 16 KB, swizzled chunks
    __shared__ unsigned short Bs[128 * 64];   // 16 KB

    const int t    = threadIdx.x;     // 0..511
    const int lane = t & 63;
    const int w    = t >> 6;          // 0..7
    const int wr   = w >> 2;          // 0,1  : 64-row half
    const int wc   = w & 3;           // 0..3 : 32-col quarter
    const int g    = lane >> 4;       // quad 0..3
    const int lrow = lane & 15;

    const int bm = blockIdx.x;   // token tiles (32)
    const int bn = blockIdx.y;   // feature tiles (8)

    const unsigned short* __restrict__ Arow = (which == 2) ? W  : xb;
    const unsigned short* __restrict__ Brow = (which == 2) ? xb : W;
    const int am0 = (which == 2) ? bn * 128 : bm * 128;
    const int bn0 = (which == 2) ? bm * 128 : bn * 128;

    const int srow = t >> 3;                              // 0..63
    const int sc   = ((t & 7) ^ ((t >> 3) & 7)) << 3;     // short offset in row
    const unsigned short* gA = Arow + (size_t)(am0 + srow) * HID_ + sc;
    const unsigned short* gB = Brow + (size_t)(bn0 + srow) * HID_ + sc;

    const f32x4 zero = {0.f, 0.f, 0.f, 0.f};
    f32x4 acc[4][2];
    #pragma unroll
    for (int i = 0; i < 4; ++i)
        #pragma unroll
        for (int j = 0; j < 2; ++j) acc[i][j] = zero;

    for (int k0 = 0; k0 < HID_; k0 += 64) {
        __syncthreads();   // prev iter's ds_reads done before overwrite
        #pragma unroll
        for (int i = 0; i < 2; ++i) {
            load_lds16(gA + (size_t)(i * 64) * HID_ + k0, (char*)As + i * 8192 + t * 16);
            load_lds16(gB + (size_t)(i * 64) * HID_ + k0, (char*)Bs + i * 8192 + t * 16);
        }
        __syncthreads();   // staged data visible (drains vmcnt)

        #pragma unroll
        for (int ks = 0; ks < 2; ++ks) {
            bf16x8 af[4], bf[2];
            #pragma unroll
            for (int i = 0; i < 4; ++i) {
                const int row = wr * 64 + i * 16 + lrow;
                af[i] = *(const bf16x8*)&As[row * 64 + (((ks * 4 + g) ^ (row & 7)) << 3)];
            }
            #pragma unroll
            for (int j = 0; j < 2; ++j) {
                const int row = wc * 32 + j * 16 + lrow;
                bf[j] = *(const bf16x8*)&Bs[row * 64 + (((ks * 4 + g) ^ (row & 7)) << 3)];
            }
            #pragma unroll
            for (int i = 0; i < 4; ++i)
                #pragma unroll
                for (int j = 0; j < 2; ++j)
                    acc[i][j] = __builtin_amdgcn_mfma_f32_16x16x32_bf16(
                        af[i], bf[j], acc[i][j], 0, 0, 0);
        }
    }

    // Epilogue. D layout: col=lane&15 (n side), row=(lane>>4)*4+r (m side)
    const int col   = lane & 15;
    const int rbase = (lane >> 4) << 2;
    if (which == 2) {
        #pragma unroll
        for (int i = 0; i < 4; ++i) {
            #pragma unroll
            for (int r = 0; r < 4; ++r) {
                const int feat = bn * 128 + wr * 64 + i * 16 + rbase + r;
                const int h = feat >> 6, d = feat & 63;
                const float bias_v = bias[feat];
                #pragma unroll
                for (int j = 0; j < 2; ++j) {
                    const int tok = bm * 128 + wc * 32 + j * 16 + col;
                    const int b = tok >> 10, s = tok & 1023;
                    vtout[((size_t)((b << 4) + h) << 16) + ((size_t)d << 10) + s] =
                        f2bf(acc[i][j][r] + bias_v);
                }
            }
        }
    } else {
        #pragma unroll
        for (int j = 0; j < 2; ++j) {
            const int feat = bn * 128 + wc * 32 + j * 16 + col;
            const int h = feat >> 6, d = feat & 63;
            const float bias_v = bias[feat];
            #pragma unroll
            for (int i = 0; i < 4; ++i) {
                const int tok0 = bm * 128 + wr * 64 + i * 16 + rbase;
                #pragma unroll
                for (int r = 0; r < 4; ++r) {
                    const int tok = tok0 + r;
                    const int b = tok >> 10, s = tok & 1023;
                    const size_t off = ((size_t)((b << 4) + h) << 16) + ((size_t)s << 6) + d;
                    const float val = acc[i][j][r] + bias_v;
                    if (which == 0) qout[off] = f2bf(val);
                    else            kout[off] = f2bf(val);
                }
            }
        }
    }
}

// ---------------------------------------------------------------------------
// Kernel 2: flash attention, 32x32x16 MFMA, in-register softmax (T12).
// ROUND CHANGE (occupancy): R3's rewrite was neutral because grid 512 x
// 256-thr = 2 blocks/CU = 2 waves/SIMD -- latency-bound (serial MFMA ->
// softmax -> MFMA -> barrier chain can't be hidden). Fixed-offset softmax
// (no running max) makes O and l = sum(exp) ADDITIVE across key ranges, so
// split keys in two: blockIdx.z = khalf processes keys [khalf*512, +512),
// writing unnormalized partial O (f32) + partial l to workspace. Grid 1024
// blocks -> 4 blocks/CU; LDS trimmed to 34.5 KB (Mts 512 entries, Ls gone)
// -> 138 KB/CU fits; __launch_bounds__(256,4) caps VGPR at 128 -> 16
// waves/CU = 4 waves/SIMD. Per-element exp/pack arithmetic unchanged.
// attn_combine: out = (O0+O1) / (l0+l1), ~48 MB mostly L3-resident.
// ---------------------------------------------------------------------------
__global__ __launch_bounds__(256, 4) void attn_mfma(
    const unsigned short* __restrict__ Q, const unsigned short* __restrict__ K,
    const unsigned short* __restrict__ Vt, const float* __restrict__ mask,
    float* __restrict__ Opart, float* __restrict__ lpart)
{
    __shared__ unsigned short Ks[2][64 * 64];   // 16 KB ping-pong (64-key tile)
    __shared__ unsigned short Vts[2][64 * 64];  // 16 KB ping-pong [d][key]
    __shared__ float Mts[512];                  // 2 KB  (2 - mask)*1e6, local keys

    const int t    = threadIdx.x;    // 0..255
    const int lane = t & 63;
    const int w    = t >> 6;         // 0..3
    const int q31  = lane & 31;
    const int hl   = lane >> 5;      // half-wave 0/1

    const int bh = blockIdx.x;       // x-major: all q-tiles of a bh on one XCD
    const int b  = bh >> 4;
    const int h  = bh & 15;
    const int q0w = (blockIdx.y << 7) + (w << 5);   // wave's 32-query base
    const int kb0 = blockIdx.z << 9;                // key half base (0 or 512)

    const unsigned short* __restrict__ qg = Q  + ((size_t)bh << 16);
    const unsigned short* __restrict__ kg = K  + ((size_t)bh << 16);
    const unsigned short* __restrict__ vg = Vt + ((size_t)bh << 16);

    // ---- Q^T B-operand in registers: qreg[kc] = Q[q0w+q31][kc*16+hl*8 .. +7]
    bf16x8 qreg[4];
    {
        const unsigned short* qp = qg + ((size_t)(q0w + q31) << 6);
        #pragma unroll
        for (int kc = 0; kc < 4; ++kc)
            qreg[kc] = *(const bf16x8*)&qp[kc * 16 + (hl << 3)];
    }

    // ---- hoisted swizzled LDS byte offsets (same for K and Vt tiles):
    //      frag(kc) at row=q31 (+32 per kb/hb), 8-key chunk (2*kc+hl)^(row&7)
    int fro[4];
    #pragma unroll
    for (int kc = 0; kc < 4; ++kc)
        fro[kc] = q31 * 128 + ((((kc << 1) + hl) ^ (q31 & 7)) << 4);

    // ---- staging addresses (pre-swizzled global source, linear LDS dest)
    const int srow = t >> 3;                       // 0..31
    const int c8   = ((t & 7) ^ (srow & 7)) << 3;  // chunk, short offset
    const unsigned short* kst = kg + (size_t)(kb0 + srow) * 64 + c8;   // +i*2048 +kt*4096
    const unsigned short* vst = vg + (size_t)srow * 1024 + kb0 + c8;   // +i*32768 +kt*64

    f32x16 O[2];
    #pragma unroll
    for (int i = 0; i < 16; ++i) { O[0][i] = 0.f; O[1][i] = 0.f; }
    float lacc = 0.f;

    // ---- prologue: stage tile 0, precompute mask term for this key half
    #pragma unroll
    for (int i = 0; i < 2; ++i) {
        load_lds16(kst + i * 2048,  (char*)Ks[0]  + i * 4096 + t * 16);
        load_lds16(vst + i * 32768, (char*)Vts[0] + i * 4096 + t * 16);
    }
    #pragma unroll
    for (int i = 0; i < 2; ++i) {
        const int key = t + i * 256;
        Mts[key] = (2.0f - mask[(b << 10) + kb0 + key]) * 1.0e6f;
    }
    __syncthreads();   // tile 0 + Mts visible (drains vmcnt + lgkm)

    for (int kt = 0; kt < 8; ++kt) {
        const int cur = kt & 1;

        // ---- issue next tile's stage into the other buffer (hidden by compute)
        if (kt < 7) {
            #pragma unroll
            for (int i = 0; i < 2; ++i) {
                load_lds16(kst + i * 2048 + (size_t)(kt + 1) * 4096,
                           (char*)Ks[cur ^ 1] + i * 4096 + t * 16);
                load_lds16(vst + i * 32768 + (size_t)(kt + 1) * 64,
                           (char*)Vts[cur ^ 1] + i * 4096 + t * 16);
            }
        }

        const char* Kb = (const char*)Ks[cur];
        const char* Vb = (const char*)Vts[cur];

        // ---- S^T = K Q^T : sacc[kb] covers keys kb*32..+31 x 32 queries ----
        f32x16 sacc[2];
        #pragma unroll
        for (int i = 0; i < 16; ++i) { sacc[0][i] = 0.f; sacc[1][i] = 0.f; }
        #pragma unroll
        for (int kb = 0; kb < 2; ++kb) {
            bf16x8 kf[4];
            #pragma unroll
            for (int kc = 0; kc < 4; ++kc)
                kf[kc] = *(const bf16x8*)(Kb + kb * 4096 + fro[kc]);
            __builtin_amdgcn_s_setprio(1);
            #pragma unroll
            for (int kc = 0; kc < 4; ++kc)
                sacc[kb] = __builtin_amdgcn_mfma_f32_32x32x16_bf16(
                    kf[kc], qreg[kc], sacc[kb], 0, 0, 0);
            __builtin_amdgcn_s_setprio(0);
        }

        // ---- softmax (exact per-element ops as before) + in-reg P pack ----
        // lane holds p for q=q31, local key = kt*64 + kb*32 + (r&3)+8*(r>>2)+4*hl
        bf16x8 pf[4];
        #pragma unroll
        for (int kb = 0; kb < 2; ++kb) {
            unsigned u[4][2];
            #pragma unroll
            for (int rq = 0; rq < 4; ++rq) {
                const f32x4 m4 = *(const f32x4*)&Mts[kt * 64 + kb * 32 + rq * 8 + (hl << 2)];
                float p[4];
                #pragma unroll
                for (int r = 0; r < 4; ++r) {
                    const float sv = sacc[kb][rq * 4 + r] * 0.125f - m4[r];
                    p[r] = __expf(sv + 1.0e6f);
                }
                lacc += (p[0] + p[1]) + (p[2] + p[3]);
                u[rq][0] = pk_bf16(p[0], p[1]);
                u[rq][1] = pk_bf16(p[2], p[3]);
            }
            // permlane32_swap: build A-operand frags for k-chunks kb*2, kb*2+1
            #pragma unroll
            for (int c = 0; c < 2; ++c) {
                unsigned w0 = u[2 * c][0], w2 = u[2 * c + 1][0];
                plswap(w0, w2);                       // -> words 0 and 2
                unsigned w1 = u[2 * c][1], w3 = u[2 * c + 1][1];
                plswap(w1, w3);                       // -> words 1 and 3
                union { unsigned u[4]; bf16x8 v; } f;
                f.u[0] = w0; f.u[1] = w1; f.u[2] = w2; f.u[3] = w3;
                pf[kb * 2 + c] = f.v;
            }
        }

        // ---- O += P V : B=V[key][d] from Vt[d][key] tile, C col = d ----
        #pragma unroll
        for (int hb = 0; hb < 2; ++hb) {
            bf16x8 vf[4];
            #pragma unroll
            for (int kc = 0; kc < 4; ++kc)
                vf[kc] = *(const bf16x8*)(Vb + hb * 4096 + fro[kc]);
            __builtin_amdgcn_s_setprio(1);
            #pragma unroll
            for (int kc = 0; kc < 4; ++kc)
                O[hb] = __builtin_amdgcn_mfma_f32_32x32x16_bf16(
                    pf[kc], vf[kc], O[hb], 0, 0, 0);
            __builtin_amdgcn_s_setprio(0);
        }

        __syncthreads();   // drains vmcnt: tile kt+1 staged; buf[cur] reusable
    }

    // ---- epilogue: partial l and UNNORMALIZED partial O to workspace ----
    const float l = lacc + __shfl_xor(lacc, 32);
    if (lane < 32)
        lpart[(((size_t)blockIdx.z << 6) + bh) * 1024 + q0w + q31] = l;
    float* op = Opart + ((size_t)blockIdx.z << 22);
    #pragma unroll
    for (int r = 0; r < 16; ++r) {
        const int qr = (r & 3) + ((r >> 2) << 3) + (hl << 2);   // C row
        const size_t base = (((size_t)(b << 10) + (q0w + qr)) << 10) + (h << 6);
        op[base + q31]      = O[0][r];
        op[base + 32 + q31] = O[1][r];
    }
}

// ---------------------------------------------------------------------------
// Kernel 3: combine key-half partials: out = (O0 + O1) / (l0 + l1)
// ---------------------------------------------------------------------------
__global__ __launch_bounds__(256) void attn_combine(
    const float* __restrict__ Opart, const float* __restrict__ lpart,
    float* __restrict__ out)
{
    const int i = blockIdx.x * 256 + threadIdx.x;   // 0 .. NTOK*HID/4-1
    const int f4 = i << 2;                          // float index
    const int tok = f4 >> 10;                       // b*1024 + s
    const int hid = f4 & 1023;
    const int bh  = ((tok >> 10) << 4) + (hid >> 6);
    const int q   = tok & 1023;

    const float l = lpart[bh * 1024 + q] + lpart[(64 * 1024) + bh * 1024 + q];
    const float inv = 1.0f / l;
    const f32x4 o0 = *(const f32x4*)&Opart[f4];
    const f32x4 o1 = *(const f32x4*)&Opart[(1 << 22) + f4];
    f32x4 o;
    #pragma unroll
    for (int k = 0; k < 4; ++k) o[k] = (o0[k] + o1[k]) * inv;
    *(f32x4*)&out[f4] = o;
}

// ---------------------------------------------------------------------------
extern "C" void kernel_launch(void* const* d_in, const int* in_sizes, int n_in,
                              void* d_out, int out_size, void* d_ws, size_t ws_size,
                              hipStream_t stream) {
    const float* hs   = (const float*)d_in[0];
    const float* mask = (const float*)d_in[1];
    const float* Wq   = (const float*)d_in[2];
    const float* bq   = (const float*)d_in[3];
    const float* Wk   = (const float*)d_in[4];
    const float* bk   = (const float*)d_in[5];
    const float* Wv   = (const float*)d_in[6];
    const float* bv   = (const float*)d_in[7];
    float* out = (float*)d_out;

    // Workspace: xb@0 (8MB) | wqb@8 wkb@10 wvb@12 (2MB each) |
    //            qb@14 (8MB) | kb@22 (8MB) | vtb@30 (8MB) |
    //            Opart@40 (32MB: 2 x 16MB) | lpart@72 (512KB)  = 72.5 MB
    char* ws = (char*)d_ws;
    unsigned short* xb  = (unsigned short*)(ws);
    unsigned short* wqb = (unsigned short*)(ws + ((size_t)8  << 20));
    unsigned short* wkb = (unsigned short*)(ws + ((size_t)10 << 20));
    unsigned short* wvb = (unsigned short*)(ws + ((size_t)12 << 20));
    unsigned short* qb  = (unsigned short*)(ws + ((size_t)14 << 20));
    unsigned short* kb  = (unsigned short*)(ws + ((size_t)22 << 20));
    unsigned short* vtb = (unsigned short*)(ws + ((size_t)30 << 20));
    float* Opart = (float*)(ws + ((size_t)40 << 20));
    float* lpart = (float*)(ws + ((size_t)72 << 20));

    cvt_all<<<dim3(4096, 4), 256, 0, stream>>>(hs, Wq, Wk, Wv, xb, wqb, wkb, wvb);
    qkv_gemm_mfma<<<dim3(NTOK / 128, HID_ / 128, 3), 512, 0, stream>>>(
        xb, wqb, bq, wkb, bk, wvb, bv, qb, kb, vtb);
    attn_mfma<<<dim3(B_ * NH_, S_ / 128, 2), 256, 0, stream>>>(
        qb, kb, vtb, mask, Opart, lpart);
    attn_combine<<<dim3(NTOK * HID_ / 4 / 256), 256, 0, stream>>>(Opart, lpart, out);
}

// Round 5
// 147.696 us; speedup vs baseline: 1.0351x; 1.0351x over previous
//
#include <hip/hip_runtime.h>
#include <math.h>

// Problem constants
#define B_ 4
#define S_ 1024
#define HID_ 1024
#define NH_ 16
#define HD_ 64
#define NTOK (B_ * S_)           // 4096

typedef __attribute__((ext_vector_type(4))) float f32x4;
typedef __attribute__((ext_vector_type(16))) float f32x16;
typedef __attribute__((ext_vector_type(8))) short bf16x8;   // 8 bf16 = 4 VGPRs

__device__ __forceinline__ unsigned short f2bf(float f) {
    union { float f; unsigned int u; } v; v.f = f;
    unsigned int r = v.u + 0x7fffu + ((v.u >> 16) & 1u);   // RNE
    return (unsigned short)(r >> 16);
}

// Packed f32->bf16 (RNE). gfx950 has v_cvt_pk_bf16_f32; fall back to software.
#if __has_builtin(__builtin_amdgcn_cvt_pk_bf16_f32)
__device__ __forceinline__ unsigned int pk_bf16(float a, float b) {
    auto v = __builtin_amdgcn_cvt_pk_bf16_f32(a, b);   // elem0=a (low), elem1=b (high)
    union { decltype(v) v; unsigned int u; } cv; cv.v = v;
    return cv.u;
}
#else
__device__ __forceinline__ unsigned int pk_bf16(float a, float b) {
    return (unsigned int)f2bf(a) | ((unsigned int)f2bf(b) << 16);
}
#endif

// permlane32_swap: (a,b) -> a' = {a.lo, b.lo}, b' = {a.hi, b.hi}
#if __has_builtin(__builtin_amdgcn_permlane32_swap)
__device__ __forceinline__ void plswap(unsigned &a, unsigned &b) {
    typedef __attribute__((ext_vector_type(2))) int v2i;
    v2i r = __builtin_amdgcn_permlane32_swap((int)a, (int)b, false, false);
    a = (unsigned)r[0]; b = (unsigned)r[1];
}
#else
__device__ __forceinline__ void plswap(unsigned &a, unsigned &b) {
    const unsigned bl = __shfl_xor(b, 32);
    const unsigned ah = __shfl_xor(a, 32);
    const bool hi = ((threadIdx.x & 63) >> 5) != 0;
    const unsigned na = hi ? bl : a;
    const unsigned nb = hi ? b  : ah;
    a = na; b = nb;
}
#endif

// async global->LDS, 16 B per lane. LDS dest = wave-uniform base + lane*16.
__device__ __forceinline__ void load_lds16(const void* g, void* l) {
    __builtin_amdgcn_global_load_lds(
        (const __attribute__((address_space(1))) unsigned int*)(uintptr_t)g,
        (__attribute__((address_space(3))) unsigned int*)(uintptr_t)l,
        16, 0, 0);
}

// ---------------------------------------------------------------------------
// Kernel 0: f32 -> bf16 convert for x, Wq, Wk, Wv  (packed cvt)
// ---------------------------------------------------------------------------
__global__ __launch_bounds__(256) void cvt_all(
    const float* __restrict__ x, const float* __restrict__ wq,
    const float* __restrict__ wk, const float* __restrict__ wv,
    unsigned short* __restrict__ xb, unsigned short* __restrict__ wqb,
    unsigned short* __restrict__ wkb, unsigned short* __restrict__ wvb)
{
    const int which = blockIdx.y;
    const float* src = which == 0 ? x : which == 1 ? wq : which == 2 ? wk : wv;
    unsigned short* dst = which == 0 ? xb : which == 1 ? wqb : which == 2 ? wkb : wvb;
    const int n4 = (which == 0) ? (NTOK * HID_ / 4) : (HID_ * HID_ / 4);
    int i = blockIdx.x * 256 + threadIdx.x;
    if (i < n4) {
        float4 f = ((const float4*)src)[i];
        uint2 o;
        o.x = pk_bf16(f.x, f.y);
        o.y = pk_bf16(f.z, f.w);
        ((uint2*)dst)[i] = o;
    }
}

// ---------------------------------------------------------------------------
// Kernel 1: QKV projection, bf16 MFMA. 128x128 tile, BK=64, XOR-swizzled LDS,
// 512 threads / 8 waves (wave owns 64x32). Unchanged.
// ---------------------------------------------------------------------------
__global__ __launch_bounds__(512, 6) void qkv_gemm_mfma(
    const unsigned short* __restrict__ xb,
    const unsigned short* __restrict__ Wqb, const float* __restrict__ bq,
    const unsigned short* __restrict__ Wkb, const float* __restrict__ bk,
    const unsigned short* __restrict__ Wvb, const float* __restrict__ bv,
    unsigned short* __restrict__ qout, unsigned short* __restrict__ kout,
    unsigned short* __restrict__ vtout)
{
    const int which = blockIdx.z;
    const unsigned short* __restrict__ W = which == 0 ? Wqb : which == 1 ? Wkb : Wvb;
    const float* __restrict__ bias       = which == 0 ? bq  : which == 1 ? bk  : bv;

    __shared__ unsigned short As[128 * 64];   // 16 KB, swizzled chunks
    __shared__ unsigned short Bs[128 * 64];   // 16 KB

    const int t    = threadIdx.x;     // 0..511
    const int lane = t & 63;
    const int w    = t >> 6;          // 0..7
    const int wr   = w >> 2;          // 0,1  : 64-row half
    const int wc   = w & 3;           // 0..3 : 32-col quarter
    const int g    = lane >> 4;       // quad 0..3
    const int lrow = lane & 15;

    const int bm = blockIdx.x;   // token tiles (32)
    const int bn = blockIdx.y;   // feature tiles (8)

    const unsigned short* __restrict__ Arow = (which == 2) ? W  : xb;
    const unsigned short* __restrict__ Brow = (which == 2) ? xb : W;
    const int am0 = (which == 2) ? bn * 128 : bm * 128;
    const int bn0 = (which == 2) ? bm * 128 : bn * 128;

    const int srow = t >> 3;                              // 0..63
    const int sc   = ((t & 7) ^ ((t >> 3) & 7)) << 3;     // short offset in row
    const unsigned short* gA = Arow + (size_t)(am0 + srow) * HID_ + sc;
    const unsigned short* gB = Brow + (size_t)(bn0 + srow) * HID_ + sc;

    const f32x4 zero = {0.f, 0.f, 0.f, 0.f};
    f32x4 acc[4][2];
    #pragma unroll
    for (int i = 0; i < 4; ++i)
        #pragma unroll
        for (int j = 0; j < 2; ++j) acc[i][j] = zero;

    for (int k0 = 0; k0 < HID_; k0 += 64) {
        __syncthreads();   // prev iter's ds_reads done before overwrite
        #pragma unroll
        for (int i = 0; i < 2; ++i) {
            load_lds16(gA + (size_t)(i * 64) * HID_ + k0, (char*)As + i * 8192 + t * 16);
            load_lds16(gB + (size_t)(i * 64) * HID_ + k0, (char*)Bs + i * 8192 + t * 16);
        }
        __syncthreads();   // staged data visible (drains vmcnt)

        #pragma unroll
        for (int ks = 0; ks < 2; ++ks) {
            bf16x8 af[4], bf[2];
            #pragma unroll
            for (int i = 0; i < 4; ++i) {
                const int row = wr * 64 + i * 16 + lrow;
                af[i] = *(const bf16x8*)&As[row * 64 + (((ks * 4 + g) ^ (row & 7)) << 3)];
            }
            #pragma unroll
            for (int j = 0; j < 2; ++j) {
                const int row = wc * 32 + j * 16 + lrow;
                bf[j] = *(const bf16x8*)&Bs[row * 64 + (((ks * 4 + g) ^ (row & 7)) << 3)];
            }
            #pragma unroll
            for (int i = 0; i < 4; ++i)
                #pragma unroll
                for (int j = 0; j < 2; ++j)
                    acc[i][j] = __builtin_amdgcn_mfma_f32_16x16x32_bf16(
                        af[i], bf[j], acc[i][j], 0, 0, 0);
        }
    }

    // Epilogue. D layout: col=lane&15 (n side), row=(lane>>4)*4+r (m side)
    const int col   = lane & 15;
    const int rbase = (lane >> 4) << 2;
    if (which == 2) {
        #pragma unroll
        for (int i = 0; i < 4; ++i) {
            #pragma unroll
            for (int r = 0; r < 4; ++r) {
                const int feat = bn * 128 + wr * 64 + i * 16 + rbase + r;
                const int h = feat >> 6, d = feat & 63;
                const float bias_v = bias[feat];
                #pragma unroll
                for (int j = 0; j < 2; ++j) {
                    const int tok = bm * 128 + wc * 32 + j * 16 + col;
                    const int b = tok >> 10, s = tok & 1023;
                    vtout[((size_t)((b << 4) + h) << 16) + ((size_t)d << 10) + s] =
                        f2bf(acc[i][j][r] + bias_v);
                }
            }
        }
    } else {
        #pragma unroll
        for (int j = 0; j < 2; ++j) {
            const int feat = bn * 128 + wc * 32 + j * 16 + col;
            const int h = feat >> 6, d = feat & 63;
            const float bias_v = bias[feat];
            #pragma unroll
            for (int i = 0; i < 4; ++i) {
                const int tok0 = bm * 128 + wr * 64 + i * 16 + rbase;
                #pragma unroll
                for (int r = 0; r < 4; ++r) {
                    const int tok = tok0 + r;
                    const int b = tok >> 10, s = tok & 1023;
                    const size_t off = ((size_t)((b << 4) + h) << 16) + ((size_t)s << 6) + d;
                    const float val = acc[i][j][r] + bias_v;
                    if (which == 0) qout[off] = f2bf(val);
                    else            kout[off] = f2bf(val);
                }
            }
        }
    }
}

// ---------------------------------------------------------------------------
// Kernel 2: flash attention, 32x32x16 MFMA, in-register softmax (T12).
// ROUND CHANGE: IN-BLOCK key split. R4's khalf grid split gave 16 waves/CU
// but paid a 10 us combine kernel (48 MB HBM round-trip). Now: 512-thr
// blocks, 8 waves; waves 0-3 = keys 0-511, waves 4-7 = keys 512-1023, same
// 128 queries. Partials combine through LDS at kernel end (B-waves write
// unnormalized O + l into the K buffers after the final barrier; A-waves
// add, normalize, store). Arithmetic + summation order identical to R4:
// out = (OA + OB) / (lA + lB); per-element exp/pack ops unchanged.
// LDS: Ks ping-pong per half 32 KB + Vts single-buffer per half 16 KB +
// Mts 4 KB = 52 KB < 64 KB cap -> 2 blocks/CU = 16 waves/CU (as R4).
// V(kt) stage is issued at iter top, covered by S^T+softmax before the
// mid-iter barrier that precedes PV. 2 barriers/iter, 8 iters.
// ---------------------------------------------------------------------------
__global__ __launch_bounds__(512, 4) void attn_mfma(
    const unsigned short* __restrict__ Q, const unsigned short* __restrict__ K,
    const unsigned short* __restrict__ Vt, const float* __restrict__ mask,
    float* __restrict__ out)
{
    __shared__ unsigned short Ks[2][2][64 * 64];   // [half][buf] 32 KB ping-pong
    __shared__ unsigned short Vts[2][64 * 64];     // [half] 16 KB single-buffer
    __shared__ float Mts[1024];                    // 4 KB (2 - mask)*1e6 per key

    const int t    = threadIdx.x;    // 0..511
    const int lane = t & 63;
    const int w    = t >> 6;         // 0..7
    const int kh   = w >> 2;         // key half: 0 = keys 0-511, 1 = 512-1023
    const int pw   = w & 3;          // pair index: which 32-query group
    const int q31  = lane & 31;
    const int hl   = lane >> 5;      // half-wave 0/1

    const int bh = blockIdx.x;       // x-major: all q-tiles of a bh on one XCD
    const int b  = bh >> 4;
    const int h  = bh & 15;
    const int q0w = (blockIdx.y << 7) + (pw << 5);   // wave's 32-query base

    const unsigned short* __restrict__ qg = Q  + ((size_t)bh << 16);
    const unsigned short* __restrict__ kg = K  + ((size_t)bh << 16);
    const unsigned short* __restrict__ vg = Vt + ((size_t)bh << 16);

    // ---- Q^T B-operand in registers: qreg[kc] = Q[q0w+q31][kc*16+hl*8 .. +7]
    bf16x8 qreg[4];
    {
        const unsigned short* qp = qg + ((size_t)(q0w + q31) << 6);
        #pragma unroll
        for (int kc = 0; kc < 4; ++kc)
            qreg[kc] = *(const bf16x8*)&qp[kc * 16 + (hl << 3)];
    }

    // ---- hoisted swizzled LDS byte offsets (same for K and Vt tiles):
    //      frag(kc) at row=q31 (+32 per kb/hb), 8-key chunk (2*kc+hl)^(row&7)
    int fro[4];
    #pragma unroll
    for (int kc = 0; kc < 4; ++kc)
        fro[kc] = q31 * 128 + ((((kc << 1) + hl) ^ (q31 & 7)) << 4);

    // ---- staging addresses (pre-swizzled global source, linear LDS dest)
    // Each thread stages 16 B into all 4 tile buffers (KA', KB', VA, VB).
    const int srow = t >> 3;                       // 0..63 (key row / d row)
    const int c8   = ((t & 7) ^ (srow & 7)) << 3;  // chunk, short offset
    const unsigned short* kstat = kg + (size_t)srow * 64 + c8;    // +hh*32768 +kt*4096
    const unsigned short* vstat = vg + (size_t)srow * 1024 + c8;  // +hh*512   +kt*64

    f32x16 O[2];
    #pragma unroll
    for (int i = 0; i < 16; ++i) { O[0][i] = 0.f; O[1][i] = 0.f; }
    float lacc = 0.f;

    // ---- prologue: stage K tile 0 (both halves), precompute mask term
    #pragma unroll
    for (int hh = 0; hh < 2; ++hh)
        load_lds16(kstat + hh * 32768, (char*)Ks[hh][0] + t * 16);
    #pragma unroll
    for (int i = 0; i < 2; ++i) {
        const int key = t + i * 512;
        Mts[key] = (2.0f - mask[(b << 10) + key]) * 1.0e6f;
    }
    __syncthreads();   // K tile 0 + Mts visible (drains vmcnt + lgkm)

    for (int kt = 0; kt < 8; ++kt) {
        const int cur = kt & 1;

        // ---- issue stages: V(kt) (read this iter, after barrier #1) and
        //      K(kt+1) prefetch into the other K buffer
        #pragma unroll
        for (int hh = 0; hh < 2; ++hh) {
            load_lds16(vstat + hh * 512 + (size_t)kt * 64, (char*)Vts[hh] + t * 16);
            if (kt < 7)
                load_lds16(kstat + hh * 32768 + (size_t)(kt + 1) * 4096,
                           (char*)Ks[hh][cur ^ 1] + t * 16);
        }

        const char* Kb = (const char*)Ks[kh][cur];
        const char* Vb = (const char*)Vts[kh];

        // ---- S^T = K Q^T : sacc[kb] covers keys kb*32..+31 x 32 queries ----
        f32x16 sacc[2];
        #pragma unroll
        for (int i = 0; i < 16; ++i) { sacc[0][i] = 0.f; sacc[1][i] = 0.f; }
        #pragma unroll
        for (int kb = 0; kb < 2; ++kb) {
            bf16x8 kf[4];
            #pragma unroll
            for (int kc = 0; kc < 4; ++kc)
                kf[kc] = *(const bf16x8*)(Kb + kb * 4096 + fro[kc]);
            __builtin_amdgcn_s_setprio(1);
            #pragma unroll
            for (int kc = 0; kc < 4; ++kc)
                sacc[kb] = __builtin_amdgcn_mfma_f32_32x32x16_bf16(
                    kf[kc], qreg[kc], sacc[kb], 0, 0, 0);
            __builtin_amdgcn_s_setprio(0);
        }

        // ---- softmax (exact per-element ops as before) + in-reg P pack ----
        // lane holds p for q=q31, key = kh*512 + kt*64 + kb*32 + (r&3)+8*(r>>2)+4*hl
        bf16x8 pf[4];
        #pragma unroll
        for (int kb = 0; kb < 2; ++kb) {
            unsigned u[4][2];
            #pragma unroll
            for (int rq = 0; rq < 4; ++rq) {
                const f32x4 m4 = *(const f32x4*)&Mts[(kh << 9) + kt * 64 + kb * 32 + rq * 8 + (hl << 2)];
                float p[4];
                #pragma unroll
                for (int r = 0; r < 4; ++r) {
                    const float sv = sacc[kb][rq * 4 + r] * 0.125f - m4[r];
                    p[r] = __expf(sv + 1.0e6f);
                }
                lacc += (p[0] + p[1]) + (p[2] + p[3]);
                u[rq][0] = pk_bf16(p[0], p[1]);
                u[rq][1] = pk_bf16(p[2], p[3]);
            }
            // permlane32_swap: build A-operand frags for k-chunks kb*2, kb*2+1
            #pragma unroll
            for (int c = 0; c < 2; ++c) {
                unsigned w0 = u[2 * c][0], w2 = u[2 * c + 1][0];
                plswap(w0, w2);                       // -> words 0 and 2
                unsigned w1 = u[2 * c][1], w3 = u[2 * c + 1][1];
                plswap(w1, w3);                       // -> words 1 and 3
                union { unsigned uu[4]; bf16x8 v; } f;
                f.uu[0] = w0; f.uu[1] = w1; f.uu[2] = w2; f.uu[3] = w3;
                pf[kb * 2 + c] = f.v;
            }
        }

        __syncthreads();   // barrier #1: V(kt) + K(kt+1) staged & visible

        // ---- O += P V : B=V[key][d] from Vt[d][key] tile, C col = d ----
        #pragma unroll
        for (int hb = 0; hb < 2; ++hb) {
            bf16x8 vf[4];
            #pragma unroll
            for (int kc = 0; kc < 4; ++kc)
                vf[kc] = *(const bf16x8*)(Vb + hb * 4096 + fro[kc]);
            __builtin_amdgcn_s_setprio(1);
            #pragma unroll
            for (int kc = 0; kc < 4; ++kc)
                O[hb] = __builtin_amdgcn_mfma_f32_32x32x16_bf16(
                    pf[kc], vf[kc], O[hb], 0, 0, 0);
            __builtin_amdgcn_s_setprio(0);
        }

        __syncthreads();   // barrier #2: V reads done -> safe to restage V;
                           // K[cur] reads done -> safe to overwrite next iter
    }

    // ---- epilogue: in-block combine of the two key halves --------------
    // B-waves (kh=1) write unnormalized O + l to LDS (aliased onto Ks/Vts,
    // safe after barrier #2 of the last iter); A-waves add, normalize, store.
    float* Osh = (float*)&Ks[0][0][0];     // 4 pairs x 32 q x 64 d = 32 KB
    float* Lsh = (float*)&Vts[0][0];       // [0..127]=B's l, [128..255]=A's l
    const float l = lacc + __shfl_xor(lacc, 32);
    if (kh == 1) {
        #pragma unroll
        for (int r = 0; r < 16; ++r) {
            const int qr = (r & 3) + ((r >> 2) << 3) + (hl << 2);
            Osh[pw * 2048 + qr * 64 + q31]      = O[0][r];
            Osh[pw * 2048 + qr * 64 + 32 + q31] = O[1][r];
        }
        if (lane < 32) Lsh[pw * 32 + q31] = l;
    } else {
        if (lane < 32) Lsh[128 + pw * 32 + q31] = l;
    }
    __syncthreads();
    if (kh == 0) {
        #pragma unroll
        for (int r = 0; r < 16; ++r) {
            const int qr = (r & 3) + ((r >> 2) << 3) + (hl << 2);
            const float inv = 1.0f / (Lsh[128 + pw * 32 + qr] + Lsh[pw * 32 + qr]);
            const size_t base = (((size_t)(b << 10) + (q0w + qr)) << 10) + (h << 6);
            out[base + q31]      = (O[0][r] + Osh[pw * 2048 + qr * 64 + q31])      * inv;
            out[base + 32 + q31] = (O[1][r] + Osh[pw * 2048 + qr * 64 + 32 + q31]) * inv;
        }
    }
}

// ---------------------------------------------------------------------------
extern "C" void kernel_launch(void* const* d_in, const int* in_sizes, int n_in,
                              void* d_out, int out_size, void* d_ws, size_t ws_size,
                              hipStream_t stream) {
    const float* hs   = (const float*)d_in[0];
    const float* mask = (const float*)d_in[1];
    const float* Wq   = (const float*)d_in[2];
    const float* bq   = (const float*)d_in[3];
    const float* Wk   = (const float*)d_in[4];
    const float* bk   = (const float*)d_in[5];
    const float* Wv   = (const float*)d_in[6];
    const float* bv   = (const float*)d_in[7];
    float* out = (float*)d_out;

    // Workspace: xb@0 (8MB) | wqb@8 wkb@10 wvb@12 (2MB each) |
    //            qb@14 (8MB) | kb@22 (8MB) | vtb@30 (8MB)  = 38 MB
    char* ws = (char*)d_ws;
    unsigned short* xb  = (unsigned short*)(ws);
    unsigned short* wqb = (unsigned short*)(ws + ((size_t)8  << 20));
    unsigned short* wkb = (unsigned short*)(ws + ((size_t)10 << 20));
    unsigned short* wvb = (unsigned short*)(ws + ((size_t)12 << 20));
    unsigned short* qb  = (unsigned short*)(ws + ((size_t)14 << 20));
    unsigned short* kb  = (unsigned short*)(ws + ((size_t)22 << 20));
    unsigned short* vtb = (unsigned short*)(ws + ((size_t)30 << 20));

    cvt_all<<<dim3(4096, 4), 256, 0, stream>>>(hs, Wq, Wk, Wv, xb, wqb, wkb, wvb);
    qkv_gemm_mfma<<<dim3(NTOK / 128, HID_ / 128, 3), 512, 0, stream>>>(
        xb, wqb, bq, wkb, bk, wvb, bv, qb, kb, vtb);
    attn_mfma<<<dim3(B_ * NH_, S_ / 128), 512, 0, stream>>>(qb, kb, vtb, mask, out);
}